// Round 1
// baseline (704.498 us; speedup 1.0000x reference)
//
#include <hip/hip_runtime.h>
#include <math.h>

#define BB 32
#define TT 720
#define NNN 321
#define KK 25
#define PP 12

constexpr int L0 = BB * TT * NNN;          // 7,395,840
constexpr int L1 = (L0 + 15) / 2;          // 3,697,927
constexpr int L2 = (L1 + 15) / 2;          // 1,848,971
constexpr int L3 = (L2 + 15) / 2;          // 924,493
constexpr unsigned KMED = (unsigned)((L1 - 1) / 2 + 1);  // 1-indexed rank of median
constexpr float AA = 0.85f;

// Daubechies-like 16-tap analysis low-pass (from reference)
constexpr float DLO[16] = {
    -0.0033824159510061256f, -0.0005421323317911481f, 0.03169508781149298f,
    0.007607487324917605f,  -0.1432942383508097f,    -0.061273359067658524f,
    0.4813596512583722f,     0.7771857517005235f,     0.36444189483533895f,
    -0.05194583810770904f,  -0.027219029917056003f,   0.049137179673607506f,
    0.003808752013890615f,  -0.01495225833704823f,   -0.0003029205147213668f,
    0.0018899503327594609f };

// ---------------- moving average + residual ----------------
__global__ void mavg_kernel(const float* __restrict__ x,
                            float* __restrict__ trend,
                            float* __restrict__ res) {
    int idx = blockIdx.x * blockDim.x + threadIdx.x;
    if (idx >= L0) return;
    int n  = idx % NNN;
    int bt = idx / NNN;
    int t  = bt % TT;
    int b  = bt / TT;
    const float* xb = x + (size_t)b * TT * NNN + n;
    float sum = 0.f;
#pragma unroll
    for (int dt = -PP; dt <= PP; ++dt) {
        int tt = t + dt;
        tt = tt < 0 ? 0 : (tt >= TT ? TT - 1 : tt);
        sum += xb[(size_t)tt * NNN];
    }
    float tr = sum * (1.0f / (float)KK);
    trend[idx] = tr;
    res[idx] = x[idx] - tr;
}

// ---------------- DWT: one level, 2 signals (blockIdx.y) ----------------
// ca[o] = sum_j DLO[j] * a[sym(2o+1-j)] ; cd with DEC_HI[j] = (j odd ? +1 : -1)*DLO[15-j]
__global__ void dwt_kernel(const float* __restrict__ in0,
                           const float* __restrict__ in1,
                           int Lin, int Lout,
                           float* __restrict__ ca, float* __restrict__ cd) {
    int o = blockIdx.x * blockDim.x + threadIdx.x;
    int s = blockIdx.y;
    if (o >= Lout) return;
    const float* a = s ? in1 : in0;
    float slo = 0.f, shi = 0.f;
    int base = 2 * o + 1;
#pragma unroll
    for (int j = 0; j < 16; ++j) {
        int idx = base - j;
        if (idx < 0) idx = -1 - idx;
        if (idx >= Lin) idx = 2 * Lin - 1 - idx;
        float v = a[idx];
        slo = fmaf(DLO[j], v, slo);
        float h = (j & 1) ? DLO[15 - j] : -DLO[15 - j];
        shi = fmaf(h, v, shi);
    }
    ca[s * Lout + o] = slo;
    cd[s * Lout + o] = shi;
}

// ---------------- soft threshold helper ----------------
__device__ __forceinline__ float sthr(float d, float lam, float alam) {
    float ad = fabsf(d);
    return (ad >= lam) ? copysignf(ad - alam, d) : 0.f;
}

// ---------------- IDWT pair: outputs r=2q, 2q+1 share coeff reads ----------------
__device__ __forceinline__ void idwt_pair(const float* __restrict__ ca,
                                          const float* __restrict__ cd,
                                          int q, float lam, float alam,
                                          float& v0, float& v1) {
    float a0 = 0.f, a1 = 0.f;
#pragma unroll
    for (int p = 0; p < 8; ++p) {
        float a = ca[q + p];
        float d = sthr(cd[q + p], lam, alam);
        a0 = fmaf(a, DLO[2 * p + 1], a0);
        a0 = fmaf(d, DLO[14 - 2 * p], a0);
        a1 = fmaf(a, DLO[2 * p], a1);
        a1 = fmaf(d, -DLO[15 - 2 * p], a1);
    }
    v0 = a0; v1 = a1;
}

// IDWT middle levels: writes rec[s*M + r], r < M
__global__ void idwt_mid(const float* __restrict__ coefA,
                         const float* __restrict__ coefD,
                         int Lc, int M,
                         float* __restrict__ out,
                         const float* __restrict__ lamArr) {
    int q = blockIdx.x * blockDim.x + threadIdx.x;
    int s = blockIdx.y;
    int r0 = 2 * q;
    if (r0 >= M) return;
    float lam = lamArr[s];
    float alam = AA * lam;
    const float* ca = coefA + (size_t)s * Lc;
    const float* cd = coefD + (size_t)s * Lc;
    float v0, v1;
    idwt_pair(ca, cd, q, lam, alam, v0, v1);
    float* o = out + (size_t)s * M;
    o[r0] = v0;
    if (r0 + 1 < M) o[r0 + 1] = v1;
}

// IDWT final level: writes (orig - nn) and nn directly to d_out
__global__ void idwt_final(const float* __restrict__ coefA,
                           const float* __restrict__ coefD,
                           const float* __restrict__ trend,
                           const float* __restrict__ res,
                           float* __restrict__ out,
                           const float* __restrict__ lamArr) {
    int q = blockIdx.x * blockDim.x + threadIdx.x;
    int s = blockIdx.y;
    int r0 = 2 * q;
    if (r0 >= L0) return;
    float lam = lamArr[s];
    float alam = AA * lam;
    const float* ca = coefA + (size_t)s * L1;
    const float* cd = coefD + (size_t)s * L1;
    float v0, v1;
    idwt_pair(ca, cd, q, lam, alam, v0, v1);
    const float* orig = s ? res : trend;
    float* o_diff = out + (size_t)(2 * s) * L0;
    float* o_nn   = out + (size_t)(2 * s + 1) * L0;
    int r1 = r0 + 1;  // L0 even -> always valid
    o_nn[r0] = v0;  o_diff[r0] = orig[r0] - v0;
    o_nn[r1] = v1;  o_diff[r1] = orig[r1] - v1;
}

// ---------------- exact median via 4x8-bit radix select ----------------
__global__ void init_median(unsigned* __restrict__ hist,
                            unsigned* __restrict__ prefix,
                            unsigned* __restrict__ kArr) {
    int t = threadIdx.x;
    if (t < 512) hist[t] = 0;
    if (t < 2) { prefix[t] = 0; kArr[t] = KMED; }
}

__global__ void hist_kernel(const float* __restrict__ d,
                            unsigned* __restrict__ hist,
                            const unsigned* __restrict__ prefix,
                            int shift) {
    int s = blockIdx.y;
    const float* ds = d + (size_t)s * L1;
    __shared__ unsigned sh[256];
    sh[threadIdx.x] = 0;
    __syncthreads();
    unsigned pref = prefix[s];
    int stride = gridDim.x * blockDim.x;
    for (int i = blockIdx.x * blockDim.x + threadIdx.x; i < L1; i += stride) {
        unsigned u = __float_as_uint(fabsf(ds[i]));
        bool match = (shift == 24) || ((u >> (shift + 8)) == (pref >> (shift + 8)));
        if (match) atomicAdd(&sh[(u >> shift) & 0xFF], 1u);
    }
    __syncthreads();
    atomicAdd(&hist[s * 256 + threadIdx.x], sh[threadIdx.x]);
}

__global__ void select_kernel(unsigned* __restrict__ hist,
                              unsigned* __restrict__ prefix,
                              unsigned* __restrict__ kArr,
                              float* __restrict__ lamArr,
                              int shift) {
    int s = blockIdx.x;
    int t = threadIdx.x;
    __shared__ unsigned sc[256];
    unsigned c = hist[s * 256 + t];
    hist[s * 256 + t] = 0;   // re-zero for next pass
    sc[t] = c;
    __syncthreads();
    for (int off = 1; off < 256; off <<= 1) {
        unsigned v = (t >= off) ? sc[t - off] : 0u;
        __syncthreads();
        sc[t] += v;
        __syncthreads();
    }
    unsigned incl = sc[t], excl = incl - c;
    unsigned k = kArr[s];
    if (excl < k && incl >= k) {
        unsigned npref = prefix[s] | ((unsigned)t << shift);
        prefix[s] = npref;
        kArr[s] = k - excl;
        if (shift == 0) {
            float med = __uint_as_float(npref);
            float sigma = med / 0.6745f;
            lamArr[s] = sigma * sqrtf(2.0f * logf((float)L0));
        }
    }
}

extern "C" void kernel_launch(void* const* d_in, const int* in_sizes, int n_in,
                              void* d_out, int out_size, void* d_ws, size_t ws_size,
                              hipStream_t stream) {
    const float* x = (const float*)d_in[0];
    float* out = (float*)d_out;
    float* w = (float*)d_ws;

    float* trend = w;
    float* res   = w + (size_t)L0;
    float* ca1   = w + 2 * (size_t)L0;            // also rec1 (stride L1)
    float* cd1   = ca1 + 2 * (size_t)L1;
    float* ca2   = cd1 + 2 * (size_t)L1;          // also rec2 (stride L2)
    float* cd2   = ca2 + 2 * (size_t)L2;
    float* ca3   = cd2 + 2 * (size_t)L2;
    float* cd3   = ca3 + 2 * (size_t)L3;
    float* fend  = cd3 + 2 * (size_t)L3;
    unsigned* hist   = (unsigned*)fend;
    unsigned* prefix = hist + 512;
    unsigned* kArr   = prefix + 2;
    float*    lamArr = (float*)(kArr + 2);

    dim3 b256(256);

    init_median<<<1, 512, 0, stream>>>(hist, prefix, kArr);
    mavg_kernel<<<(L0 + 255) / 256, b256, 0, stream>>>(x, trend, res);
    dwt_kernel<<<dim3((L1 + 255) / 256, 2), b256, 0, stream>>>(trend, res, L0, L1, ca1, cd1);

    for (int pass = 0; pass < 4; ++pass) {
        int shift = 24 - 8 * pass;
        hist_kernel<<<dim3(2048, 2), b256, 0, stream>>>(cd1, hist, prefix, shift);
        select_kernel<<<2, 256, 0, stream>>>(hist, prefix, kArr, lamArr, shift);
    }

    dwt_kernel<<<dim3((L2 + 255) / 256, 2), b256, 0, stream>>>(ca1, ca1 + L1, L1, L2, ca2, cd2);
    dwt_kernel<<<dim3((L3 + 255) / 256, 2), b256, 0, stream>>>(ca2, ca2 + L2, L2, L3, ca3, cd3);

    idwt_mid<<<dim3(((L2 + 1) / 2 + 255) / 256, 2), b256, 0, stream>>>(ca3, cd3, L3, L2, ca2, lamArr);
    idwt_mid<<<dim3(((L1 + 1) / 2 + 255) / 256, 2), b256, 0, stream>>>(ca2, cd2, L2, L1, ca1, lamArr);
    idwt_final<<<dim3((L0 / 2 + 255) / 256, 2), b256, 0, stream>>>(ca1, cd1, trend, res, out, lamArr);
}

// Round 2
// 440.756 us; speedup vs baseline: 1.5984x; 1.5984x over previous
//
#include <hip/hip_runtime.h>
#include <math.h>

#define BB 32
#define TT 720
#define NNN 321
#define KK 25
#define PP 12

constexpr int L0 = BB * TT * NNN;          // 7,395,840
constexpr int L1 = (L0 + 15) / 2;          // 3,697,927
constexpr int L2 = (L1 + 15) / 2;          // 1,848,971
constexpr int L3 = (L2 + 15) / 2;          // 924,493
constexpr unsigned KMED = (unsigned)((L1 - 1) / 2 + 1);  // 1-indexed rank of median
constexpr float AA = 0.85f;

// 16-tap analysis low-pass (from reference)
constexpr float DLO[16] = {
    -0.0033824159510061256f, -0.0005421323317911481f, 0.03169508781149298f,
    0.007607487324917605f,  -0.1432942383508097f,    -0.061273359067658524f,
    0.4813596512583722f,     0.7771857517005235f,     0.36444189483533895f,
    -0.05194583810770904f,  -0.027219029917056003f,   0.049137179673607506f,
    0.003808752013890615f,  -0.01495225833704823f,   -0.0003029205147213668f,
    0.0018899503327594609f };

// ---------------- moving average + residual ----------------
__global__ void mavg_kernel(const float* __restrict__ x,
                            float* __restrict__ trend,
                            float* __restrict__ res) {
    int idx = blockIdx.x * blockDim.x + threadIdx.x;
    if (idx >= L0) return;
    int n  = idx % NNN;
    int bt = idx / NNN;
    int t  = bt % TT;
    int b  = bt / TT;
    const float* xb = x + (size_t)b * TT * NNN + n;
    float sum = 0.f;
#pragma unroll
    for (int dt = -PP; dt <= PP; ++dt) {
        int tt = t + dt;
        tt = tt < 0 ? 0 : (tt >= TT ? TT - 1 : tt);
        sum += xb[(size_t)tt * NNN];
    }
    float tr = sum * (1.0f / (float)KK);
    trend[idx] = tr;
    res[idx] = x[idx] - tr;
}

// ---------------- DWT: one level, 2 signals (blockIdx.y) ----------------
__global__ void dwt_kernel(const float* __restrict__ in0,
                           const float* __restrict__ in1,
                           int Lin, int Lout,
                           float* __restrict__ ca, float* __restrict__ cd) {
    int o = blockIdx.x * blockDim.x + threadIdx.x;
    int s = blockIdx.y;
    if (o >= Lout) return;
    const float* a = s ? in1 : in0;
    float slo = 0.f, shi = 0.f;
    int base = 2 * o + 1;
#pragma unroll
    for (int j = 0; j < 16; ++j) {
        int idx = base - j;
        if (idx < 0) idx = -1 - idx;
        if (idx >= Lin) idx = 2 * Lin - 1 - idx;
        float v = a[idx];
        slo = fmaf(DLO[j], v, slo);
        float h = (j & 1) ? DLO[15 - j] : -DLO[15 - j];
        shi = fmaf(h, v, shi);
    }
    ca[s * Lout + o] = slo;
    cd[s * Lout + o] = shi;
}

// ---------------- soft threshold helper ----------------
__device__ __forceinline__ float sthr(float d, float lam, float alam) {
    float ad = fabsf(d);
    return (ad >= lam) ? copysignf(ad - alam, d) : 0.f;
}

// ---------------- IDWT pair: outputs r=2q, 2q+1 share coeff reads ----------------
__device__ __forceinline__ void idwt_pair(const float* __restrict__ ca,
                                          const float* __restrict__ cd,
                                          int q, float lam, float alam,
                                          float& v0, float& v1) {
    float a0 = 0.f, a1 = 0.f;
#pragma unroll
    for (int p = 0; p < 8; ++p) {
        float a = ca[q + p];
        float d = sthr(cd[q + p], lam, alam);
        a0 = fmaf(a, DLO[2 * p + 1], a0);
        a0 = fmaf(d, DLO[14 - 2 * p], a0);
        a1 = fmaf(a, DLO[2 * p], a1);
        a1 = fmaf(d, -DLO[15 - 2 * p], a1);
    }
    v0 = a0; v1 = a1;
}

__global__ void idwt_mid(const float* __restrict__ coefA,
                         const float* __restrict__ coefD,
                         int Lc, int M,
                         float* __restrict__ out,
                         const float* __restrict__ lamArr) {
    int q = blockIdx.x * blockDim.x + threadIdx.x;
    int s = blockIdx.y;
    int r0 = 2 * q;
    if (r0 >= M) return;
    float lam = lamArr[s];
    float alam = AA * lam;
    const float* ca = coefA + (size_t)s * Lc;
    const float* cd = coefD + (size_t)s * Lc;
    float v0, v1;
    idwt_pair(ca, cd, q, lam, alam, v0, v1);
    float* o = out + (size_t)s * M;
    o[r0] = v0;
    if (r0 + 1 < M) o[r0 + 1] = v1;
}

__global__ void idwt_final(const float* __restrict__ coefA,
                           const float* __restrict__ coefD,
                           const float* __restrict__ trend,
                           const float* __restrict__ res,
                           float* __restrict__ out,
                           const float* __restrict__ lamArr) {
    int q = blockIdx.x * blockDim.x + threadIdx.x;
    int s = blockIdx.y;
    int r0 = 2 * q;
    if (r0 >= L0) return;
    float lam = lamArr[s];
    float alam = AA * lam;
    const float* ca = coefA + (size_t)s * L1;
    const float* cd = coefD + (size_t)s * L1;
    float v0, v1;
    idwt_pair(ca, cd, q, lam, alam, v0, v1);
    const float* orig = s ? res : trend;
    float* o_diff = out + (size_t)(2 * s) * L0;
    float* o_nn   = out + (size_t)(2 * s + 1) * L0;
    int r1 = r0 + 1;  // L0 even -> always valid
    o_nn[r0] = v0;  o_diff[r0] = orig[r0] - v0;
    o_nn[r1] = v1;  o_diff[r1] = orig[r1] - v1;
}

// ---------------- exact median via 12+12+8-bit radix select ----------------
// hist: 2 signals x 4096 bins (overlays dead ca2 region during median phase)
__global__ void init_median(unsigned* __restrict__ hist,
                            unsigned* __restrict__ prefix,
                            unsigned* __restrict__ kArr) {
    int t = blockIdx.x * blockDim.x + threadIdx.x;
    if (t < 8192) hist[t] = 0;
    if (t < 2) { prefix[t] = 0; kArr[t] = KMED; }
}

// pass 0: digit = bits[31:20] (sign is 0 after fabs)
// pass 1: match bits[31:20], digit = bits[19:8]
// pass 2: match bits[31:8],  digit = bits[7:0]
__global__ void hist_kernel(const float* __restrict__ d,
                            unsigned* __restrict__ hist,
                            const unsigned* __restrict__ prefix,
                            int pass) {
    int s = blockIdx.y;
    const float* ds = d + (size_t)s * L1;
    __shared__ unsigned sh[4096];
    for (int b = threadIdx.x; b < 4096; b += 256) sh[b] = 0;
    __syncthreads();
    unsigned pref = pass ? prefix[s] : 0u;
    int stride = gridDim.x * blockDim.x;
    for (int i = blockIdx.x * blockDim.x + threadIdx.x; i < L1; i += stride) {
        unsigned u = __float_as_uint(fabsf(ds[i]));
        if (pass == 0) {
            atomicAdd(&sh[u >> 20], 1u);
        } else if (pass == 1) {
            if ((u >> 20) == (pref >> 20)) atomicAdd(&sh[(u >> 8) & 0xFFFu], 1u);
        } else {
            if ((u >> 8) == (pref >> 8)) atomicAdd(&sh[u & 0xFFu], 1u);
        }
    }
    __syncthreads();
    // skip-zero reduction: atomic count scales with distinct values, not bins
    for (int b = threadIdx.x; b < 4096; b += 256) {
        unsigned c = sh[b];
        if (c) atomicAdd(&hist[s * 4096 + b], c);
    }
}

__global__ void select_kernel(unsigned* __restrict__ hist,
                              unsigned* __restrict__ prefix,
                              unsigned* __restrict__ kArr,
                              float* __restrict__ lamArr,
                              int nbins, int shift) {
    int s = blockIdx.x;
    int t = threadIdx.x;
    __shared__ unsigned sc[256];
    __shared__ unsigned base_s;
    if (t == 0) base_s = 0;
    __syncthreads();
    unsigned k = kArr[s];
    for (int c0 = 0; c0 < nbins; c0 += 256) {
        unsigned c = hist[s * 4096 + c0 + t];
        hist[s * 4096 + c0 + t] = 0;   // re-zero for next pass
        sc[t] = c;
        __syncthreads();
        for (int off = 1; off < 256; off <<= 1) {
            unsigned v = (t >= off) ? sc[t - off] : 0u;
            __syncthreads();
            sc[t] += v;
            __syncthreads();
        }
        unsigned incl = base_s + sc[t];
        unsigned excl = incl - c;
        // cumulative crosses k exactly once over the whole scan
        if (excl < k && incl >= k) {
            unsigned npref = prefix[s] | ((unsigned)(c0 + t) << shift);
            prefix[s] = npref;
            kArr[s] = k - excl;
            if (shift == 0) {
                float med = __uint_as_float(npref);
                float sigma = med / 0.6745f;
                lamArr[s] = sigma * sqrtf(2.0f * logf((float)L0));
            }
        }
        __syncthreads();
        if (t == 255) base_s += sc[255];
        __syncthreads();
    }
}

extern "C" void kernel_launch(void* const* d_in, const int* in_sizes, int n_in,
                              void* d_out, int out_size, void* d_ws, size_t ws_size,
                              hipStream_t stream) {
    const float* x = (const float*)d_in[0];
    float* out = (float*)d_out;
    float* w = (float*)d_ws;

    float* trend = w;
    float* res   = w + (size_t)L0;
    float* ca1   = w + 2 * (size_t)L0;            // also rec1 (stride L1)
    float* cd1   = ca1 + 2 * (size_t)L1;
    float* ca2   = cd1 + 2 * (size_t)L1;          // also rec2 (stride L2); hist overlays here pre-dwt2
    float* cd2   = ca2 + 2 * (size_t)L2;
    float* ca3   = cd2 + 2 * (size_t)L2;
    float* cd3   = ca3 + 2 * (size_t)L3;
    float* fend  = cd3 + 2 * (size_t)L3;
    unsigned* hist   = (unsigned*)ca2;            // 8192 u32 = 32 KB, dead before dwt2
    unsigned* prefix = (unsigned*)fend;           // survives to the end
    unsigned* kArr   = prefix + 2;
    float*    lamArr = (float*)(kArr + 2);

    dim3 b256(256);

    init_median<<<32, b256, 0, stream>>>(hist, prefix, kArr);
    mavg_kernel<<<(L0 + 255) / 256, b256, 0, stream>>>(x, trend, res);
    dwt_kernel<<<dim3((L1 + 255) / 256, 2), b256, 0, stream>>>(trend, res, L0, L1, ca1, cd1);

    // 3-pass exact radix-select median of |cd1| per signal
    hist_kernel<<<dim3(512, 2), b256, 0, stream>>>(cd1, hist, prefix, 0);
    select_kernel<<<2, b256, 0, stream>>>(hist, prefix, kArr, lamArr, 4096, 20);
    hist_kernel<<<dim3(512, 2), b256, 0, stream>>>(cd1, hist, prefix, 1);
    select_kernel<<<2, b256, 0, stream>>>(hist, prefix, kArr, lamArr, 4096, 8);
    hist_kernel<<<dim3(512, 2), b256, 0, stream>>>(cd1, hist, prefix, 2);
    select_kernel<<<2, b256, 0, stream>>>(hist, prefix, kArr, lamArr, 256, 0);

    // remaining decomposition levels (hist region becomes ca2 again here)
    dwt_kernel<<<dim3((L2 + 255) / 256, 2), b256, 0, stream>>>(ca1, ca1 + L1, L1, L2, ca2, cd2);
    dwt_kernel<<<dim3((L3 + 255) / 256, 2), b256, 0, stream>>>(ca2, ca2 + L2, L2, L3, ca3, cd3);

    idwt_mid<<<dim3(((L2 + 1) / 2 + 255) / 256, 2), b256, 0, stream>>>(ca3, cd3, L3, L2, ca2, lamArr);
    idwt_mid<<<dim3(((L1 + 1) / 2 + 255) / 256, 2), b256, 0, stream>>>(ca2, cd2, L2, L1, ca1, lamArr);
    idwt_final<<<dim3((L0 / 2 + 255) / 256, 2), b256, 0, stream>>>(ca1, cd1, trend, res, out, lamArr);
}

// Round 3
// 363.261 us; speedup vs baseline: 1.9394x; 1.2133x over previous
//
#include <hip/hip_runtime.h>
#include <math.h>

#define BB 32
#define TT 720
#define NNN 321
#define KK 25
#define PP 12
#define TCH 48   // T-chunk per thread in mavg; 720 = 15 * 48

constexpr int L0 = BB * TT * NNN;          // 7,395,840
constexpr int L1 = (L0 + 15) / 2;          // 3,697,927
constexpr int L2 = (L1 + 15) / 2;          // 1,848,971
constexpr int L3 = (L2 + 15) / 2;          // 924,493
constexpr unsigned KMED = (unsigned)((L1 - 1) / 2 + 1);  // 1-indexed rank of median
constexpr float AA = 0.85f;

// 16-tap analysis low-pass (from reference)
constexpr float DLO[16] = {
    -0.0033824159510061256f, -0.0005421323317911481f, 0.03169508781149298f,
    0.007607487324917605f,  -0.1432942383508097f,    -0.061273359067658524f,
    0.4813596512583722f,     0.7771857517005235f,     0.36444189483533895f,
    -0.05194583810770904f,  -0.027219029917056003f,   0.049137179673607506f,
    0.003808752013890615f,  -0.01495225833704823f,   -0.0003029205147213668f,
    0.0018899503327594609f };

// ---------------- moving average + residual (running sum along T) ----------------
// Each thread owns a TCH-long T-chunk of one (b,n) column. Tap reuse is
// within-thread (L1-local) -> no cross-XCD L2 duplication.
__global__ void mavg_kernel(const float* __restrict__ x,
                            float* __restrict__ trend,
                            float* __restrict__ res) {
    constexpr int NCH = TT / TCH;                 // 15
    int gid = blockIdx.x * blockDim.x + threadIdx.x;
    if (gid >= BB * NCH * NNN) return;
    int n    = gid % NNN;
    int rest = gid / NNN;
    int ch   = rest % NCH;
    int b    = rest / NCH;
    int t0   = ch * TCH;
    const float* xb = x + (size_t)b * TT * NNN + n;
    // initial 25-tap window centered at t0 (clamped)
    float sum = 0.f;
#pragma unroll
    for (int dt = -PP; dt <= PP; ++dt) {
        int tt = t0 + dt;
        tt = tt < 0 ? 0 : (tt >= TT ? TT - 1 : tt);
        sum += xb[(size_t)tt * NNN];
    }
    size_t base = (size_t)b * TT * NNN + (size_t)t0 * NNN + n;
    for (int i = 0; i < TCH; ++i) {
        int t = t0 + i;
        float tr = sum * (1.0f / (float)KK);
        size_t idx = base + (size_t)i * NNN;
        trend[idx] = tr;
        res[idx] = xb[(size_t)t * NNN] - tr;
        int tp = t + 1 + PP; if (tp > TT - 1) tp = TT - 1;
        int tm = t - PP;     if (tm < 0)      tm = 0;
        sum += xb[(size_t)tp * NNN] - xb[(size_t)tm * NNN];
    }
}

// ---------------- DWT: one level, 2 signals (blockIdx.y), 2 outputs/thread ----
__global__ void dwt_kernel(const float* __restrict__ in0,
                           const float* __restrict__ in1,
                           int Lin, int Lout,
                           float* __restrict__ ca, float* __restrict__ cd) {
    int o0 = (blockIdx.x * blockDim.x + threadIdx.x) * 2;
    int s = blockIdx.y;
    if (o0 >= Lout) return;
    const float* a = s ? in1 : in0;
    // interior fast path: inputs 2*o0-14 .. 2*o0+3 all in range, both outputs valid
    if (2 * o0 - 14 >= 0 && 2 * o0 + 3 < Lin && o0 + 1 < Lout) {
        const float* p = a + 2 * o0 - 14;
        float v[18];
#pragma unroll
        for (int j = 0; j < 18; ++j) v[j] = p[j];
        float slo0 = 0.f, shi0 = 0.f, slo1 = 0.f, shi1 = 0.f;
#pragma unroll
        for (int j = 0; j < 16; ++j) {
            float h = (j & 1) ? DLO[15 - j] : -DLO[15 - j];
            slo0 = fmaf(DLO[j], v[15 - j], slo0);
            shi0 = fmaf(h,      v[15 - j], shi0);
            slo1 = fmaf(DLO[j], v[17 - j], slo1);
            shi1 = fmaf(h,      v[17 - j], shi1);
        }
        ca[(size_t)s * Lout + o0]     = slo0;
        cd[(size_t)s * Lout + o0]     = shi0;
        ca[(size_t)s * Lout + o0 + 1] = slo1;
        cd[(size_t)s * Lout + o0 + 1] = shi1;
    } else {
        int oend = (o0 + 2 < Lout) ? o0 + 2 : Lout;
        for (int o = o0; o < oend; ++o) {
            float slo = 0.f, shi = 0.f;
            int bidx = 2 * o + 1;
#pragma unroll
            for (int j = 0; j < 16; ++j) {
                int idx = bidx - j;
                if (idx < 0) idx = -1 - idx;
                if (idx >= Lin) idx = 2 * Lin - 1 - idx;
                float v = a[idx];
                slo = fmaf(DLO[j], v, slo);
                float h = (j & 1) ? DLO[15 - j] : -DLO[15 - j];
                shi = fmaf(h, v, shi);
            }
            ca[(size_t)s * Lout + o] = slo;
            cd[(size_t)s * Lout + o] = shi;
        }
    }
}

// ---------------- soft threshold helper ----------------
__device__ __forceinline__ float sthr(float d, float lam, float alam) {
    float ad = fabsf(d);
    return (ad >= lam) ? copysignf(ad - alam, d) : 0.f;
}

// ---------------- IDWT pair: outputs r=2q, 2q+1 share coeff reads ----------------
__device__ __forceinline__ void idwt_pair(const float* __restrict__ ca,
                                          const float* __restrict__ cd,
                                          int q, float lam, float alam,
                                          float& v0, float& v1) {
    float a0 = 0.f, a1 = 0.f;
#pragma unroll
    for (int p = 0; p < 8; ++p) {
        float a = ca[q + p];
        float d = sthr(cd[q + p], lam, alam);
        a0 = fmaf(a, DLO[2 * p + 1], a0);
        a0 = fmaf(d, DLO[14 - 2 * p], a0);
        a1 = fmaf(a, DLO[2 * p], a1);
        a1 = fmaf(d, -DLO[15 - 2 * p], a1);
    }
    v0 = a0; v1 = a1;
}

__global__ void idwt_mid(const float* __restrict__ coefA,
                         const float* __restrict__ coefD,
                         int Lc, int M,
                         float* __restrict__ out,
                         const float* __restrict__ lamArr) {
    int q = blockIdx.x * blockDim.x + threadIdx.x;
    int s = blockIdx.y;
    int r0 = 2 * q;
    if (r0 >= M) return;
    float lam = lamArr[s];
    float alam = AA * lam;
    const float* ca = coefA + (size_t)s * Lc;
    const float* cd = coefD + (size_t)s * Lc;
    float v0, v1;
    idwt_pair(ca, cd, q, lam, alam, v0, v1);
    float* o = out + (size_t)s * M;
    o[r0] = v0;
    if (r0 + 1 < M) o[r0 + 1] = v1;
}

__global__ void idwt_final(const float* __restrict__ coefA,
                           const float* __restrict__ coefD,
                           const float* __restrict__ trend,
                           const float* __restrict__ res,
                           float* __restrict__ out,
                           const float* __restrict__ lamArr) {
    int q = blockIdx.x * blockDim.x + threadIdx.x;
    int s = blockIdx.y;
    int r0 = 2 * q;
    if (r0 >= L0) return;
    float lam = lamArr[s];
    float alam = AA * lam;
    const float* ca = coefA + (size_t)s * L1;
    const float* cd = coefD + (size_t)s * L1;
    float v0, v1;
    idwt_pair(ca, cd, q, lam, alam, v0, v1);
    const float* orig = s ? res : trend;
    float* o_diff = out + (size_t)(2 * s) * L0;
    float* o_nn   = out + (size_t)(2 * s + 1) * L0;
    int r1 = r0 + 1;  // L0 even -> always valid
    o_nn[r0] = v0;  o_diff[r0] = orig[r0] - v0;
    o_nn[r1] = v1;  o_diff[r1] = orig[r1] - v1;
}

// ---------------- exact median via 12+12+8-bit radix select ----------------
__global__ void init_median(unsigned* __restrict__ hist,
                            unsigned* __restrict__ prefix,
                            unsigned* __restrict__ kArr) {
    int t = blockIdx.x * blockDim.x + threadIdx.x;
    if (t < 8192) hist[t] = 0;
    if (t < 2) { prefix[t] = 0; kArr[t] = KMED; }
}

// pass 0: digit = bits[31:20]; pass 1: match [31:20], digit [19:8]; pass 2: match [31:8], digit [7:0]
__global__ void hist_kernel(const float* __restrict__ d,
                            unsigned* __restrict__ hist,
                            const unsigned* __restrict__ prefix,
                            int pass) {
    int s = blockIdx.y;
    const float* ds = d + (size_t)s * L1;
    __shared__ unsigned sh[4096];
    for (int b = threadIdx.x; b < 4096; b += 256) sh[b] = 0;
    __syncthreads();
    unsigned pref = pass ? prefix[s] : 0u;
    int stride = gridDim.x * blockDim.x;
    for (int i = blockIdx.x * blockDim.x + threadIdx.x; i < L1; i += stride) {
        unsigned u = __float_as_uint(fabsf(ds[i]));
        if (pass == 0) {
            atomicAdd(&sh[u >> 20], 1u);
        } else if (pass == 1) {
            if ((u >> 20) == (pref >> 20)) atomicAdd(&sh[(u >> 8) & 0xFFFu], 1u);
        } else {
            if ((u >> 8) == (pref >> 8)) atomicAdd(&sh[u & 0xFFu], 1u);
        }
    }
    __syncthreads();
    for (int b = threadIdx.x; b < 4096; b += 256) {
        unsigned c = sh[b];
        if (c) atomicAdd(&hist[s * 4096 + b], c);
    }
}

__global__ void select_kernel(unsigned* __restrict__ hist,
                              unsigned* __restrict__ prefix,
                              unsigned* __restrict__ kArr,
                              float* __restrict__ lamArr,
                              int nbins, int shift) {
    int s = blockIdx.x;
    int t = threadIdx.x;
    __shared__ unsigned sc[256];
    __shared__ unsigned base_s;
    if (t == 0) base_s = 0;
    __syncthreads();
    unsigned k = kArr[s];
    for (int c0 = 0; c0 < nbins; c0 += 256) {
        unsigned c = hist[s * 4096 + c0 + t];
        hist[s * 4096 + c0 + t] = 0;
        sc[t] = c;
        __syncthreads();
        for (int off = 1; off < 256; off <<= 1) {
            unsigned v = (t >= off) ? sc[t - off] : 0u;
            __syncthreads();
            sc[t] += v;
            __syncthreads();
        }
        unsigned incl = base_s + sc[t];
        unsigned excl = incl - c;
        if (excl < k && incl >= k) {
            unsigned npref = prefix[s] | ((unsigned)(c0 + t) << shift);
            prefix[s] = npref;
            kArr[s] = k - excl;
            if (shift == 0) {
                float med = __uint_as_float(npref);
                float sigma = med / 0.6745f;
                lamArr[s] = sigma * sqrtf(2.0f * logf((float)L0));
            }
        }
        __syncthreads();
        if (t == 255) base_s += sc[255];
        __syncthreads();
    }
}

extern "C" void kernel_launch(void* const* d_in, const int* in_sizes, int n_in,
                              void* d_out, int out_size, void* d_ws, size_t ws_size,
                              hipStream_t stream) {
    const float* x = (const float*)d_in[0];
    float* out = (float*)d_out;
    float* w = (float*)d_ws;

    float* trend = w;
    float* res   = w + (size_t)L0;
    float* ca1   = w + 2 * (size_t)L0;            // also rec1 (stride L1)
    float* cd1   = ca1 + 2 * (size_t)L1;
    float* ca2   = cd1 + 2 * (size_t)L1;          // also rec2 (stride L2); hist overlays here pre-dwt2
    float* cd2   = ca2 + 2 * (size_t)L2;
    float* ca3   = cd2 + 2 * (size_t)L2;
    float* cd3   = ca3 + 2 * (size_t)L3;
    float* fend  = cd3 + 2 * (size_t)L3;
    unsigned* hist   = (unsigned*)ca2;            // 8192 u32 = 32 KB, dead before dwt2
    unsigned* prefix = (unsigned*)fend;           // survives to the end
    unsigned* kArr   = prefix + 2;
    float*    lamArr = (float*)(kArr + 2);

    dim3 b256(256);

    init_median<<<32, b256, 0, stream>>>(hist, prefix, kArr);
    {
        int nthreads = BB * (TT / TCH) * NNN;
        mavg_kernel<<<(nthreads + 255) / 256, b256, 0, stream>>>(x, trend, res);
    }
    dwt_kernel<<<dim3(((L1 + 1) / 2 + 255) / 256, 2), b256, 0, stream>>>(trend, res, L0, L1, ca1, cd1);

    // 3-pass exact radix-select median of |cd1| per signal
    hist_kernel<<<dim3(512, 2), b256, 0, stream>>>(cd1, hist, prefix, 0);
    select_kernel<<<2, b256, 0, stream>>>(hist, prefix, kArr, lamArr, 4096, 20);
    hist_kernel<<<dim3(512, 2), b256, 0, stream>>>(cd1, hist, prefix, 1);
    select_kernel<<<2, b256, 0, stream>>>(hist, prefix, kArr, lamArr, 4096, 8);
    hist_kernel<<<dim3(512, 2), b256, 0, stream>>>(cd1, hist, prefix, 2);
    select_kernel<<<2, b256, 0, stream>>>(hist, prefix, kArr, lamArr, 256, 0);

    dwt_kernel<<<dim3(((L2 + 1) / 2 + 255) / 256, 2), b256, 0, stream>>>(ca1, ca1 + L1, L1, L2, ca2, cd2);
    dwt_kernel<<<dim3(((L3 + 1) / 2 + 255) / 256, 2), b256, 0, stream>>>(ca2, ca2 + L2, L2, L3, ca3, cd3);

    idwt_mid<<<dim3(((L2 + 1) / 2 + 255) / 256, 2), b256, 0, stream>>>(ca3, cd3, L3, L2, ca2, lamArr);
    idwt_mid<<<dim3(((L1 + 1) / 2 + 255) / 256, 2), b256, 0, stream>>>(ca2, cd2, L2, L1, ca1, lamArr);
    idwt_final<<<dim3((L0 / 2 + 255) / 256, 2), b256, 0, stream>>>(ca1, cd1, trend, res, out, lamArr);
}

// Round 4
// 334.156 us; speedup vs baseline: 2.1083x; 1.0871x over previous
//
#include <hip/hip_runtime.h>
#include <math.h>

#define BB 32
#define TT 720
#define NNN 321
#define KK 25
#define PP 12
#define TCH 24   // T-chunk per thread in mavg; 720 = 30 * 24

constexpr int L0 = BB * TT * NNN;          // 7,395,840
constexpr int L1 = (L0 + 15) / 2;          // 3,697,927
constexpr int L2 = (L1 + 15) / 2;          // 1,848,971
constexpr int L3 = (L2 + 15) / 2;          // 924,493
constexpr unsigned KMED = (unsigned)((L1 - 1) / 2 + 1);
constexpr float AA = 0.85f;

// fused-kernel tile params
#define NC3 1024                            // ca3 outputs per block in dwt23
constexpr int LEN2T = 2 * NC3 + 32;         // ca2 tile slots (raw T0 = 2*C0-14)
constexpr int LEN1T = 4 * NC3 + 80;         // ca1 tile slots
#define NF0 4096                            // final outputs per block in idwt_fused (div by 8)
constexpr int N1T = NF0 / 2 + 8;            // 2056 rec1 tile
constexpr int N2T = N1T / 2 + 7;            // 1035 rec2 tile
constexpr int NQ3 = (N2T + 1) / 2;          // 518 rec2 pairs

// 16-tap analysis low-pass (from reference)
constexpr float DLO[16] = {
    -0.0033824159510061256f, -0.0005421323317911481f, 0.03169508781149298f,
    0.007607487324917605f,  -0.1432942383508097f,    -0.061273359067658524f,
    0.4813596512583722f,     0.7771857517005235f,     0.36444189483533895f,
    -0.05194583810770904f,  -0.027219029917056003f,   0.049137179673607506f,
    0.003808752013890615f,  -0.01495225833704823f,   -0.0003029205147213668f,
    0.0018899503327594609f };

// ---------------- moving average + residual (running sum along T) ----------------
__global__ void mavg_kernel(const float* __restrict__ x,
                            float* __restrict__ trend,
                            float* __restrict__ res) {
    constexpr int NCH = TT / TCH;                 // 30
    int gid = blockIdx.x * blockDim.x + threadIdx.x;
    if (gid >= BB * NCH * NNN) return;
    int n    = gid % NNN;
    int rest = gid / NNN;
    int ch   = rest % NCH;
    int b    = rest / NCH;
    int t0   = ch * TCH;
    const float* xb = x + (size_t)b * TT * NNN + n;
    float sum = 0.f;
#pragma unroll
    for (int dt = -PP; dt <= PP; ++dt) {
        int tt = t0 + dt;
        tt = tt < 0 ? 0 : (tt >= TT ? TT - 1 : tt);
        sum += xb[(size_t)tt * NNN];
    }
    size_t base = (size_t)b * TT * NNN + (size_t)t0 * NNN + n;
    for (int i = 0; i < TCH; ++i) {
        int t = t0 + i;
        float tr = sum * (1.0f / (float)KK);
        size_t idx = base + (size_t)i * NNN;
        trend[idx] = tr;
        res[idx] = xb[(size_t)t * NNN] - tr;
        int tp = t + 1 + PP; if (tp > TT - 1) tp = TT - 1;
        int tm = t - PP;     if (tm < 0)      tm = 0;
        sum += xb[(size_t)tp * NNN] - xb[(size_t)tm * NNN];
    }
}

// ---------------- DWT level 1: 2 signals (blockIdx.y), 2 outputs/thread ----
__global__ void dwt_kernel(const float* __restrict__ in0,
                           const float* __restrict__ in1,
                           int Lin, int Lout,
                           float* __restrict__ ca, float* __restrict__ cd) {
    int o0 = (blockIdx.x * blockDim.x + threadIdx.x) * 2;
    int s = blockIdx.y;
    if (o0 >= Lout) return;
    const float* a = s ? in1 : in0;
    if (2 * o0 - 14 >= 0 && 2 * o0 + 3 < Lin && o0 + 1 < Lout) {
        const float* p = a + 2 * o0 - 14;
        float v[18];
#pragma unroll
        for (int j = 0; j < 18; ++j) v[j] = p[j];
        float slo0 = 0.f, shi0 = 0.f, slo1 = 0.f, shi1 = 0.f;
#pragma unroll
        for (int j = 0; j < 16; ++j) {
            float h = (j & 1) ? DLO[15 - j] : -DLO[15 - j];
            slo0 = fmaf(DLO[j], v[15 - j], slo0);
            shi0 = fmaf(h,      v[15 - j], shi0);
            slo1 = fmaf(DLO[j], v[17 - j], slo1);
            shi1 = fmaf(h,      v[17 - j], shi1);
        }
        ca[(size_t)s * Lout + o0]     = slo0;
        cd[(size_t)s * Lout + o0]     = shi0;
        ca[(size_t)s * Lout + o0 + 1] = slo1;
        cd[(size_t)s * Lout + o0 + 1] = shi1;
    } else {
        int oend = (o0 + 2 < Lout) ? o0 + 2 : Lout;
        for (int o = o0; o < oend; ++o) {
            float slo = 0.f, shi = 0.f;
            int bidx = 2 * o + 1;
#pragma unroll
            for (int j = 0; j < 16; ++j) {
                int idx = bidx - j;
                if (idx < 0) idx = -1 - idx;
                if (idx >= Lin) idx = 2 * Lin - 1 - idx;
                float v = a[idx];
                slo = fmaf(DLO[j], v, slo);
                float h = (j & 1) ? DLO[15 - j] : -DLO[15 - j];
                shi = fmaf(h, v, shi);
            }
            ca[(size_t)s * Lout + o] = slo;
            cd[(size_t)s * Lout + o] = shi;
        }
    }
}

// ---------------- fused DWT levels 2+3 ----------------
// Reads ca1, writes cd2 (core), ca3, cd3. ca2 lives only in LDS.
__global__ void dwt23_kernel(const float* __restrict__ ca1,
                             float* __restrict__ cd2,
                             float* __restrict__ ca3,
                             float* __restrict__ cd3) {
    int s = blockIdx.y;
    int C0 = blockIdx.x * NC3;
    const float* a1 = ca1 + (size_t)s * L1;
    __shared__ float s1[LEN1T];
    __shared__ float s2[LEN2T];
    int T0 = 2 * C0 - 14;
    int S1 = 4 * C0 - 42; if (S1 < 0) S1 = 0;
    int E1 = 2 * (T0 + LEN2T) + 2; if (E1 > L1) E1 = L1;
    int len1 = E1 - S1;
    for (int i = threadIdx.x; i < len1; i += 256) s1[i] = a1[S1 + i];
    __syncthreads();
    // level-2 DWT into LDS ca2 tile; write cd2 core to global
    float* pcd2 = cd2 + (size_t)s * L2;
    for (int i = threadIdx.x; i < LEN2T; i += 256) {
        int e = T0 + i;
        if (e < 0 || e >= L2) continue;
        int base = 2 * e + 1;
        float slo = 0.f, shi = 0.f;
#pragma unroll
        for (int j = 0; j < 16; ++j) {
            int idx = base - j;
            if (idx < 0) idx = -1 - idx;
            if (idx >= L1) idx = 2 * L1 - 1 - idx;
            float v = s1[idx - S1];
            slo = fmaf(DLO[j], v, slo);
            float h = (j & 1) ? DLO[15 - j] : -DLO[15 - j];
            shi = fmaf(h, v, shi);
        }
        s2[i] = slo;
        if (e >= 2 * C0 && e < 2 * C0 + 2 * NC3) pcd2[e] = shi;
    }
    __syncthreads();
    // reflection fill for out-of-range ca2 tile slots (edges only)
    for (int i = threadIdx.x; i < LEN2T; i += 256) {
        int e = T0 + i;
        if (e < 0)        s2[i] = s2[(-1 - e) - T0];
        else if (e >= L2) s2[i] = s2[(2 * L2 - 1 - e) - T0];
    }
    __syncthreads();
    // level-3 DWT from LDS ca2 tile
    float* pca3 = ca3 + (size_t)s * L3;
    float* pcd3 = cd3 + (size_t)s * L3;
    for (int i = threadIdx.x; i < NC3; i += 256) {
        int o = C0 + i;
        if (o >= L3) break;
        int b2 = 2 * o + 1 - T0;
        float slo = 0.f, shi = 0.f;
#pragma unroll
        for (int j = 0; j < 16; ++j) {
            float v = s2[b2 - j];
            slo = fmaf(DLO[j], v, slo);
            float h = (j & 1) ? DLO[15 - j] : -DLO[15 - j];
            shi = fmaf(h, v, shi);
        }
        pca3[o] = slo;
        pcd3[o] = shi;
    }
}

// ---------------- soft threshold ----------------
__device__ __forceinline__ float sthr(float d, float lam, float alam) {
    float ad = fabsf(d);
    return (ad >= lam) ? copysignf(ad - alam, d) : 0.f;
}

// ---------------- fused 3-level IDWT + final outputs ----------------
// Reads ca3, cd3, cd2, cd1, trend, res; writes all 4 outputs. rec1/rec2 in LDS.
__global__ void idwt_fused(const float* __restrict__ ca3,
                           const float* __restrict__ cd3,
                           const float* __restrict__ cd2,
                           const float* __restrict__ cd1,
                           const float* __restrict__ trend,
                           const float* __restrict__ res,
                           float* __restrict__ out,
                           const float* __restrict__ lamArr) {
    int s = blockIdx.y;
    int F0 = blockIdx.x * NF0;
    float lam = lamArr[s], alam = AA * lam;
    const float* pa3 = ca3 + (size_t)s * L3;
    const float* pd3 = cd3 + (size_t)s * L3;
    const float* pd2 = cd2 + (size_t)s * L2;
    const float* pd1 = cd1 + (size_t)s * L1;
    __shared__ float r2[N2T + 1];
    __shared__ float r1[N1T];
    int A1 = F0 >> 1, A2 = F0 >> 2, Q3 = F0 >> 3;
    // stage rec2 tile from ca3/cd3 (level 3 -> 2)
    for (int i = threadIdx.x; i < NQ3; i += 256) {
        int q3 = Q3 + i;
        float a0 = 0.f, a1 = 0.f;
#pragma unroll
        for (int p = 0; p < 8; ++p) {
            int idx = q3 + p; if (idx > L3 - 1) idx = L3 - 1;
            float a = pa3[idx];
            float d = sthr(pd3[idx], lam, alam);
            a0 = fmaf(a, DLO[2 * p + 1], a0);
            a0 = fmaf(d, DLO[14 - 2 * p], a0);
            a1 = fmaf(a, DLO[2 * p], a1);
            a1 = fmaf(d, -DLO[15 - 2 * p], a1);
        }
        r2[2 * i] = a0; r2[2 * i + 1] = a1;
    }
    __syncthreads();
    // stage rec1 tile from rec2(LDS) + cd2(global) (level 2 -> 1)
    for (int i = threadIdx.x; i < N1T / 2; i += 256) {
        int q2 = A2 + i;
        float a0 = 0.f, a1 = 0.f;
#pragma unroll
        for (int p = 0; p < 8; ++p) {
            float a = r2[i + p];
            int idx = q2 + p; if (idx > L2 - 1) idx = L2 - 1;
            float d = sthr(pd2[idx], lam, alam);
            a0 = fmaf(a, DLO[2 * p + 1], a0);
            a0 = fmaf(d, DLO[14 - 2 * p], a0);
            a1 = fmaf(a, DLO[2 * p], a1);
            a1 = fmaf(d, -DLO[15 - 2 * p], a1);
        }
        r1[2 * i] = a0; r1[2 * i + 1] = a1;
    }
    __syncthreads();
    // final level from rec1(LDS) + cd1(global), write outputs
    const float* orig = s ? res : trend;
    float* o_diff = out + (size_t)(2 * s) * L0;
    float* o_nn   = out + (size_t)(2 * s + 1) * L0;
    for (int i = threadIdx.x; i < NF0 / 2; i += 256) {
        int q1 = A1 + i;
        int r0 = 2 * q1;
        if (r0 >= L0) break;
        float a0 = 0.f, a1 = 0.f;
#pragma unroll
        for (int p = 0; p < 8; ++p) {
            float a = r1[i + p];
            int idx = q1 + p; if (idx > L1 - 1) idx = L1 - 1;
            float d = sthr(pd1[idx], lam, alam);
            a0 = fmaf(a, DLO[2 * p + 1], a0);
            a0 = fmaf(d, DLO[14 - 2 * p], a0);
            a1 = fmaf(a, DLO[2 * p], a1);
            a1 = fmaf(d, -DLO[15 - 2 * p], a1);
        }
        float o0 = orig[r0], o1 = orig[r0 + 1];
        float2 nn; nn.x = a0; nn.y = a1;
        float2 df; df.x = o0 - a0; df.y = o1 - a1;
        *(float2*)(o_nn + r0)   = nn;
        *(float2*)(o_diff + r0) = df;
    }
}

// ---------------- exact median via 12+12+8-bit radix select ----------------
__global__ void init_median(unsigned* __restrict__ hist,
                            unsigned* __restrict__ prefix,
                            unsigned* __restrict__ kArr) {
    int t = blockIdx.x * blockDim.x + threadIdx.x;
    if (t < 8192) hist[t] = 0;
    if (t < 2) { prefix[t] = 0; kArr[t] = KMED; }
}

__global__ void hist_kernel(const float* __restrict__ d,
                            unsigned* __restrict__ hist,
                            const unsigned* __restrict__ prefix,
                            int pass) {
    int s = blockIdx.y;
    const float* ds = d + (size_t)s * L1;
    __shared__ unsigned sh[4096];
    for (int b = threadIdx.x; b < 4096; b += 256) sh[b] = 0;
    __syncthreads();
    unsigned pref = pass ? prefix[s] : 0u;
    int stride = gridDim.x * blockDim.x;
    for (int i = blockIdx.x * blockDim.x + threadIdx.x; i < L1; i += stride) {
        unsigned u = __float_as_uint(fabsf(ds[i]));
        if (pass == 0) {
            atomicAdd(&sh[u >> 20], 1u);
        } else if (pass == 1) {
            if ((u >> 20) == (pref >> 20)) atomicAdd(&sh[(u >> 8) & 0xFFFu], 1u);
        } else {
            if ((u >> 8) == (pref >> 8)) atomicAdd(&sh[u & 0xFFu], 1u);
        }
    }
    __syncthreads();
    for (int b = threadIdx.x; b < 4096; b += 256) {
        unsigned c = sh[b];
        if (c) atomicAdd(&hist[s * 4096 + b], c);
    }
}

// shfl-scan select: 2 barriers total
__global__ void select_kernel(unsigned* __restrict__ hist,
                              unsigned* __restrict__ prefix,
                              unsigned* __restrict__ kArr,
                              float* __restrict__ lamArr,
                              int nbins, int shift) {
    int s = blockIdx.x, t = threadIdx.x;
    int chunk = nbins >> 8;                 // 16 or 1
    unsigned loc[16];
    unsigned* hs = hist + s * 4096 + t * chunk;
    unsigned csum = 0;
    for (int j = 0; j < chunk; ++j) { loc[j] = hs[j]; hs[j] = 0; csum += loc[j]; }
    unsigned v = csum;
    int lane = t & 63, wv = t >> 6;
#pragma unroll
    for (int off = 1; off < 64; off <<= 1) {
        unsigned u = (unsigned)__shfl_up((int)v, off, 64);
        if (lane >= off) v += u;
    }
    __shared__ unsigned wsum[4];
    if (lane == 63) wsum[wv] = v;
    __syncthreads();
    unsigned base = 0;
    for (int w2 = 0; w2 < wv; ++w2) base += wsum[w2];
    unsigned incl = base + v, excl = incl - csum;
    unsigned k = kArr[s];
    if (excl < k && incl >= k) {
        unsigned run = excl;
        for (int j = 0; j < chunk; ++j) {
            if (run < k && run + loc[j] >= k) {
                unsigned digit = (unsigned)(t * chunk + j);
                unsigned npref = prefix[s] | (digit << shift);
                prefix[s] = npref;
                kArr[s] = k - run;
                if (shift == 0) {
                    float med = __uint_as_float(npref);
                    lamArr[s] = (med / 0.6745f) * sqrtf(2.0f * logf((float)L0));
                }
                break;
            }
            run += loc[j];
        }
    }
}

extern "C" void kernel_launch(void* const* d_in, const int* in_sizes, int n_in,
                              void* d_out, int out_size, void* d_ws, size_t ws_size,
                              hipStream_t stream) {
    const float* x = (const float*)d_in[0];
    float* out = (float*)d_out;
    float* w = (float*)d_ws;

    float* trend = w;
    float* res   = w + (size_t)L0;
    float* ca1   = w + 2 * (size_t)L0;
    float* cd1   = ca1 + 2 * (size_t)L1;
    float* cd2   = cd1 + 2 * (size_t)L1;
    float* ca3   = cd2 + 2 * (size_t)L2;
    float* cd3   = ca3 + 2 * (size_t)L3;
    unsigned* hist   = (unsigned*)(cd3 + 2 * (size_t)L3);
    unsigned* prefix = hist + 8192;
    unsigned* kArr   = prefix + 2;
    float*    lamArr = (float*)(kArr + 2);

    dim3 b256(256);

    init_median<<<32, b256, 0, stream>>>(hist, prefix, kArr);
    {
        int nthreads = BB * (TT / TCH) * NNN;
        mavg_kernel<<<(nthreads + 255) / 256, b256, 0, stream>>>(x, trend, res);
    }
    dwt_kernel<<<dim3(((L1 + 1) / 2 + 255) / 256, 2), b256, 0, stream>>>(trend, res, L0, L1, ca1, cd1);

    // 3-pass exact radix-select median of |cd1| per signal
    hist_kernel<<<dim3(512, 2), b256, 0, stream>>>(cd1, hist, prefix, 0);
    select_kernel<<<2, b256, 0, stream>>>(hist, prefix, kArr, lamArr, 4096, 20);
    hist_kernel<<<dim3(512, 2), b256, 0, stream>>>(cd1, hist, prefix, 1);
    select_kernel<<<2, b256, 0, stream>>>(hist, prefix, kArr, lamArr, 4096, 8);
    hist_kernel<<<dim3(512, 2), b256, 0, stream>>>(cd1, hist, prefix, 2);
    select_kernel<<<2, b256, 0, stream>>>(hist, prefix, kArr, lamArr, 256, 0);

    // fused levels 2+3 decomposition (independent of lambda)
    dwt23_kernel<<<dim3((L3 + NC3 - 1) / NC3, 2), b256, 0, stream>>>(ca1, cd2, ca3, cd3);

    // fused 3-level reconstruction + output
    idwt_fused<<<dim3((L0 + NF0 - 1) / NF0, 2), b256, 0, stream>>>(
        ca3, cd3, cd2, cd1, trend, res, out, lamArr);
}